// Round 5
// baseline (369.939 us; speedup 1.0000x reference)
//
#include <hip/hip_runtime.h>

#define EPS 1e-8f
#define THREADS 512

typedef __attribute__((ext_vector_type(8))) short short8;
typedef __attribute__((ext_vector_type(4))) float f32x4;
typedef __attribute__((ext_vector_type(8))) unsigned short u16x8;

static __device__ __forceinline__ unsigned short f2bf(float f) {
  unsigned int u = __float_as_uint(f);
  u += 0x7FFF + ((u >> 16) & 1);   // round-to-nearest-even
  return (unsigned short)(u >> 16);
}

// ---------- K1 fused: blocks 0..15 -> style matmul; blocks 16..271 -> weight prep ----------
__global__ void k_prep(const float* __restrict__ style, const float* __restrict__ mw,
                       const float* __restrict__ mb, float* __restrict__ s_out,
                       const float* __restrict__ weight, float* __restrict__ wsq,
                       unsigned short* __restrict__ wbf) {
  __shared__ float sm[2304];
  int t = threadIdx.x;
  if (blockIdx.x < 16) {
    int b = blockIdx.x;
    sm[t]       = style[b*512 + t];
    sm[t + 256] = style[b*512 + 256 + t];
    __syncthreads();
    const float4* row = (const float4*)(mw + (size_t)t*512);
    float acc = 0.f;
#pragma unroll 4
    for (int i = 0; i < 128; ++i) {
      float4 m = row[i];
      acc += m.x*sm[4*i] + m.y*sm[4*i+1] + m.z*sm[4*i+2] + m.w*sm[4*i+3];
    }
    s_out[b*256 + t] = acc + mb[t];
  } else {
    int co = blockIdx.x - 16;
    for (int q = t; q < 576; q += 256)
      *(float4*)&sm[q*4] = *(const float4*)(weight + (size_t)co*2304 + q*4);
    __syncthreads();
    int ci = t;
    int c = ci >> 6, cil = ci & 63;
    int base = ((co*128 + cil*2) ^ ((co & 7) << 4)) >> 1;
    float sum = 0.f;
#pragma unroll
    for (int r = 0; r < 9; ++r) {
      float v = sm[ci*9 + r];
      sum += v*v;
      wbf[(size_t)(c*9 + r)*16384 + base] = f2bf(v);
    }
    wsq[co*256 + ci] = sum;
  }
}

// ---------- K4: conv as implicit GEMM; x modulated+transposed in-kernel (no k_pad) ----------
// grid 256 = 16 b x 16 h-tiles; block = 256co x (4h x 64w), 8 waves (4 wm x 2 wn).
// x_lds: 6 rows(hl) x 66 gw x 64 ci bf16, XOR-swizzled; row hl maps to x row h0+hl-1.
// w_lds double-buffered; stage_w(p+1) issued before MFMA, drained by end-of-phase sync
// (drain covered by the MFMA cluster). x chunk c+1: global->reg issued at top of r==8
// phase (covered by that phase's MFMA), cvt+ds_write after the release barrier.
__global__ __launch_bounds__(512, 2)
void k_conv(const float* __restrict__ x, const unsigned short* __restrict__ wbf,
            const float* __restrict__ s_buf, const float* __restrict__ wsq,
            const float* __restrict__ bias, float* __restrict__ out) {
  __shared__ unsigned short x_lds[396*64];     // 50688 B
  __shared__ unsigned short w_lds[2*16384];    // 65536 B
  __shared__ float s_lds[256];
  __shared__ float s2s[256];
  __shared__ float dms[256];

  const int tid = threadIdx.x;
  const int lane = tid & 63;
  const int wave = tid >> 6;
  const int b = blockIdx.x >> 4;
  const int h0 = (blockIdx.x & 15) * 4;
  const int wm = wave >> 1, wn = wave & 1;
  const int l15 = lane & 15, lk = lane >> 4;
  const int oct = (tid >> 4) & 7, w4 = (tid & 15) * 4;

  auto stage_w = [&](int p) {
    const unsigned short* wsrc = wbf + (size_t)p*16384;   // pre-swizzled, linear copy
    unsigned short* dst = &w_lds[(p & 1)*16384];
#pragma unroll
    for (int it = 0; it < 4; ++it) {
      int q = it*THREADS + tid;
      __builtin_amdgcn_global_load_lds(
          (const __attribute__((address_space(1))) void*)(wsrc + (size_t)q*8),
          (__attribute__((address_space(3))) void*)&dst[(size_t)q*8],
          16, 0, 0);
    }
  };
  // load 8 float4 (8 ci x 4 w) of x row h0+hl-1 for chunk cc
  auto issue8 = [&](int cc, int hl, float4* v) {
    int h = h0 + hl - 1;
    const float* base = x + (((size_t)(b*256 + cc*64 + oct*8))*64 + h)*64 + w4;
#pragma unroll
    for (int j = 0; j < 8; ++j) v[j] = *(const float4*)(base + (size_t)j*4096);
  };
  // modulate, cvt to bf16, transpose-write into x_lds
  auto write8 = [&](int cc, int hl, const float4* v) {
    u16x8 o0, o1, o2, o3;
#pragma unroll
    for (int j = 0; j < 8; ++j) {
      float sc = s_lds[cc*64 + oct*8 + j];
      o0[j] = (short)f2bf(v[j].x * sc);
      o1[j] = (short)f2bf(v[j].y * sc);
      o2[j] = (short)f2bf(v[j].z * sc);
      o3[j] = (short)f2bf(v[j].w * sc);
    }
    int R0 = hl*66 + w4 + 1;
    { int R = R0;     *(u16x8*)((char*)x_lds + ((R*128 + oct*16) ^ ((R & 7) << 4))) = o0; }
    { int R = R0 + 1; *(u16x8*)((char*)x_lds + ((R*128 + oct*16) ^ ((R & 7) << 4))) = o1; }
    { int R = R0 + 2; *(u16x8*)((char*)x_lds + ((R*128 + oct*16) ^ ((R & 7) << 4))) = o2; }
    { int R = R0 + 3; *(u16x8*)((char*)x_lds + ((R*128 + oct*16) ^ ((R & 7) << 4))) = o3; }
  };

  const int hl0 = tid >> 7;                 // 0..3 (all 512 threads)
  const int hl1 = 4 + (tid >> 7);           // 4..5 valid for tid<256
  const bool do0 = !(hl0 == 0 && h0 == 0);                    // top halo row OOR
  const bool do1 = (tid < 256) && !(hl1 == 5 && h0 == 60);    // bottom halo row OOR

  // ---- prologue ----
  stage_w(0);
  if (tid < 256) { float sv = s_buf[b*256 + tid]; s_lds[tid] = sv; s2s[tid] = sv*sv; }
  // zero-fill: gw=0/65 columns (all hl), and OOR halo rows
  if (tid < 96) {
    int hl = tid >> 4, gw = ((tid >> 3) & 1) * 65, oc = tid & 7;
    int R = hl*66 + gw;
    *(u16x8*)((char*)x_lds + ((R*128 + oc*16) ^ ((R & 7) << 4))) = (u16x8)0;
  }
  if (h0 == 0) {
    int oc = tid & 7, gw = 1 + (tid >> 3);
    int R = gw;
    *(u16x8*)((char*)x_lds + ((R*128 + oc*16) ^ ((R & 7) << 4))) = (u16x8)0;
  }
  if (h0 == 60) {
    int oc = tid & 7, gw = 1 + (tid >> 3);
    int R = 5*66 + gw;
    *(u16x8*)((char*)x_lds + ((R*128 + oc*16) ^ ((R & 7) << 4))) = (u16x8)0;
  }
  __syncthreads();   // s_lds visible (also drains w(0) — once, cheap)

  {
    float4 v0[8], v1[8];
    if (do0) issue8(0, hl0, v0);
    if (do1) issue8(0, hl1, v1);
    // demod under the x-load latency: dms[co] = rsqrt(sum wsq[co,ci]*s^2 + eps)
    {
      int co = tid >> 1, half = tid & 1;
      const float4* row = (const float4*)(wsq + (size_t)co*256 + half*128);
      const float* sp = &s2s[half*128];
      float a = 0.f;
#pragma unroll 4
      for (int i = 0; i < 32; ++i) {
        float4 q = row[i];
        a += q.x*sp[4*i] + q.y*sp[4*i+1] + q.z*sp[4*i+2] + q.w*sp[4*i+3];
      }
      a += __shfl_xor(a, 1);
      if (half == 0) dms[co] = rsqrtf(a + EPS);
    }
    if (do0) write8(0, hl0, v0);
    if (do1) write8(0, hl1, v1);
  }
  __syncthreads();   // x(0), w(0), dms all visible

  f32x4 acc[4][8];
#pragma unroll
  for (int m = 0; m < 4; ++m)
#pragma unroll
    for (int f = 0; f < 8; ++f) acc[m][f] = (f32x4)0.f;

  // ---- main loop: 36 phases ----
  for (int c = 0; c < 4; ++c) {
    float4 v0[8], v1[8];
#pragma unroll
    for (int r = 0; r < 9; ++r) {
      int p = c*9 + r;
      if (r == 8 && c < 3) {             // issue next chunk's x loads (regs; no LDS hazard)
        if (do0) issue8(c + 1, hl0, v0);
        if (do1) issue8(c + 1, hl1, v1);
      }
      if (p < 35) stage_w(p + 1);        // async; drained by end-of-phase sync, under MFMA
      const unsigned short* wbp = &w_lds[(p & 1)*16384];
      int dh = r / 3, dw = r - dh*3;
#pragma unroll
      for (int kh = 0; kh < 2; ++kh) {
        int cio = kh*64 + lk*16;         // byte offset of this lane's 16B k-slice
        short8 a[4], bv[8];
#pragma unroll
        for (int m = 0; m < 4; ++m) {
          int co = wm*64 + m*16 + l15;
          int byte = (co*128 + cio) ^ ((co & 7) << 4);
          a[m] = *(const short8*)((const char*)wbp + byte);
        }
#pragma unroll
        for (int f = 0; f < 8; ++f) {
          int row = (wn*2 + (f >> 2) + dh)*66 + ((f & 3)*16 + l15 + dw);
          int byte = (row*128 + cio) ^ ((row & 7) << 4);
          bv[f] = *(const short8*)((const char*)x_lds + byte);
        }
        __builtin_amdgcn_s_setprio(1);
#pragma unroll
        for (int m = 0; m < 4; ++m)
#pragma unroll
          for (int f = 0; f < 8; ++f)
            acc[m][f] = __builtin_amdgcn_mfma_f32_16x16x32_bf16(a[m], bv[f], acc[m][f], 0, 0, 0);
        __builtin_amdgcn_s_setprio(0);
      }
      __syncthreads();                   // drain w(p+1) (+x regs loads at r==8); release LDS
      if (r == 8 && c < 3) {
        if (do0) write8(c + 1, hl0, v0);
        if (do1) write8(c + 1, hl1, v1);
        __syncthreads();                 // x(c+1) visible
      }
    }
  }

  // ---- epilogue: D col = lane&15 (w), row = (lane>>4)*4 + j (co offset) ----
  int colane = (lane >> 4) * 4;
#pragma unroll
  for (int m = 0; m < 4; ++m) {
    int cob = wm*64 + m*16 + colane;
    float4 d4 = *(const float4*)&dms[cob];
    float4 b4 = *(const float4*)&bias[cob];
#pragma unroll
    for (int f = 0; f < 8; ++f) {
      int h = h0 + wn*2 + (f >> 2);
      int wc = (f & 3)*16 + l15;
      float* op = out + ((size_t)(b*256 + cob)*64 + h)*64 + wc;
      op[0]     = acc[m][f][0] * d4.x + b4.x;
      op[4096]  = acc[m][f][1] * d4.y + b4.y;
      op[8192]  = acc[m][f][2] * d4.z + b4.z;
      op[12288] = acc[m][f][3] * d4.w + b4.w;
    }
  }
}

extern "C" void kernel_launch(void* const* d_in, const int* in_sizes, int n_in,
                              void* d_out, int out_size, void* d_ws, size_t ws_size,
                              hipStream_t stream) {
  const float* x      = (const float*)d_in[0];
  const float* style  = (const float*)d_in[1];
  const float* mw     = (const float*)d_in[2];
  const float* mb     = (const float*)d_in[3];
  const float* weight = (const float*)d_in[4];
  const float* bias   = (const float*)d_in[5];
  float* out = (float*)d_out;

  char* ws = (char*)d_ws;
  float* s_buf        = (float*)(ws);                             // 16 KB
  float* wsq          = (float*)(ws + 16384);                     // 256 KB
  unsigned short* wbf = (unsigned short*)(ws + 294912);           // 1.125 MB

  k_prep<<<272, 256, 0, stream>>>(style, mw, mb, s_buf, weight, wsq, wbf);
  k_conv<<<256, 512, 0, stream>>>(x, wbf, s_buf, wsq, bias, out);
}

// Round 6
// 365.542 us; speedup vs baseline: 1.0120x; 1.0120x over previous
//
#include <hip/hip_runtime.h>

#define EPS 1e-8f
#define THREADS 512

typedef __attribute__((ext_vector_type(8))) short short8;
typedef __attribute__((ext_vector_type(4))) float f32x4;
typedef __attribute__((ext_vector_type(8))) unsigned short u16x8;

static __device__ __forceinline__ unsigned short f2bf(float f) {
  unsigned int u = __float_as_uint(f);
  u += 0x7FFF + ((u >> 16) & 1);   // round-to-nearest-even
  return (unsigned short)(u >> 16);
}

// ---------- K1 fused: blocks 0..15 -> style matmul; blocks 16..271 -> weight prep ----------
__global__ void k_prep(const float* __restrict__ style, const float* __restrict__ mw,
                       const float* __restrict__ mb, float* __restrict__ s_out,
                       const float* __restrict__ weight, float* __restrict__ wsq,
                       unsigned short* __restrict__ wbf) {
  __shared__ float sm[2304];
  int t = threadIdx.x;
  if (blockIdx.x < 16) {
    int b = blockIdx.x;
    sm[t]       = style[b*512 + t];
    sm[t + 256] = style[b*512 + 256 + t];
    __syncthreads();
    const float4* row = (const float4*)(mw + (size_t)t*512);
    float acc = 0.f;
#pragma unroll 4
    for (int i = 0; i < 128; ++i) {
      float4 m = row[i];
      acc += m.x*sm[4*i] + m.y*sm[4*i+1] + m.z*sm[4*i+2] + m.w*sm[4*i+3];
    }
    s_out[b*256 + t] = acc + mb[t];
  } else {
    int co = blockIdx.x - 16;
    for (int q = t; q < 576; q += 256)
      *(float4*)&sm[q*4] = *(const float4*)(weight + (size_t)co*2304 + q*4);
    __syncthreads();
    int ci = t;
    int c = ci >> 6, cil = ci & 63;
    int base = ((co*128 + cil*2) ^ ((co & 7) << 4)) >> 1;
    float sum = 0.f;
#pragma unroll
    for (int r = 0; r < 9; ++r) {
      float v = sm[ci*9 + r];
      sum += v*v;
      wbf[(size_t)(c*9 + r)*16384 + base] = f2bf(v);
    }
    wsq[co*256 + ci] = sum;
  }
}

// ---------- K4: conv as implicit GEMM; x modulated+transposed in-kernel (no k_pad) ----------
// grid 256 = 16 b x 16 h-tiles; block = 256co x (4h x 64w), 8 waves (4 wm x 2 wn).
// x_lds: 6 rows(hl) x 66 gw x 64 ci bf16, XOR-swizzled; row hl maps to x row h0+hl-1.
// w_lds double-buffered; stage_w(p+1) issued before MFMA, drained by end-of-phase sync.
// x chunk c+1: global->reg issued at top of r==8 phase, cvt+ds_write after release barrier.
// launch_bounds(512,1): unified VGPR budget 512/wave — acc(128 AGPR) + staging regs
// must NOT spill (round-5 lesson: (512,2) capped arch VGPRs at 128 -> scratch disaster).
__global__ __launch_bounds__(512, 1)
void k_conv(const float* __restrict__ x, const unsigned short* __restrict__ wbf,
            const float* __restrict__ s_buf, const float* __restrict__ wsq,
            const float* __restrict__ bias, float* __restrict__ out) {
  __shared__ unsigned short x_lds[396*64];     // 50688 B
  __shared__ unsigned short w_lds[2*16384];    // 65536 B
  __shared__ float s_lds[256];
  __shared__ float s2s[256];
  __shared__ float dms[256];

  const int tid = threadIdx.x;
  const int lane = tid & 63;
  const int wave = tid >> 6;
  const int b = blockIdx.x >> 4;
  const int h0 = (blockIdx.x & 15) * 4;
  const int wm = wave >> 1, wn = wave & 1;
  const int l15 = lane & 15, lk = lane >> 4;
  const int oct = (tid >> 4) & 7, w4 = (tid & 15) * 4;

  auto stage_w = [&](int p) {
    const unsigned short* wsrc = wbf + (size_t)p*16384;   // pre-swizzled, linear copy
    unsigned short* dst = &w_lds[(p & 1)*16384];
#pragma unroll
    for (int it = 0; it < 4; ++it) {
      int q = it*THREADS + tid;
      __builtin_amdgcn_global_load_lds(
          (const __attribute__((address_space(1))) void*)(wsrc + (size_t)q*8),
          (__attribute__((address_space(3))) void*)&dst[(size_t)q*8],
          16, 0, 0);
    }
  };
  // load 8 float4 (8 ci x 4 w) of x row h0+hl-1 for chunk cc
  auto issue8 = [&](int cc, int hl, float4* v) {
    int h = h0 + hl - 1;
    const float* base = x + (((size_t)(b*256 + cc*64 + oct*8))*64 + h)*64 + w4;
#pragma unroll
    for (int j = 0; j < 8; ++j) v[j] = *(const float4*)(base + (size_t)j*4096);
  };
  // modulate, cvt to bf16, transpose-write into x_lds
  auto write8 = [&](int cc, int hl, const float4* v) {
    u16x8 o0, o1, o2, o3;
#pragma unroll
    for (int j = 0; j < 8; ++j) {
      float sc = s_lds[cc*64 + oct*8 + j];
      o0[j] = (short)f2bf(v[j].x * sc);
      o1[j] = (short)f2bf(v[j].y * sc);
      o2[j] = (short)f2bf(v[j].z * sc);
      o3[j] = (short)f2bf(v[j].w * sc);
    }
    int R0 = hl*66 + w4 + 1;
    { int R = R0;     *(u16x8*)((char*)x_lds + ((R*128 + oct*16) ^ ((R & 7) << 4))) = o0; }
    { int R = R0 + 1; *(u16x8*)((char*)x_lds + ((R*128 + oct*16) ^ ((R & 7) << 4))) = o1; }
    { int R = R0 + 2; *(u16x8*)((char*)x_lds + ((R*128 + oct*16) ^ ((R & 7) << 4))) = o2; }
    { int R = R0 + 3; *(u16x8*)((char*)x_lds + ((R*128 + oct*16) ^ ((R & 7) << 4))) = o3; }
  };

  const int hl0 = tid >> 7;                 // 0..3 (all 512 threads)
  const int hl1 = 4 + (tid >> 7);           // 4..5 valid for tid<256
  const bool do0 = !(hl0 == 0 && h0 == 0);                    // top halo row OOR
  const bool do1 = (tid < 256) && !(hl1 == 5 && h0 == 60);    // bottom halo row OOR

  // ---- prologue ----
  stage_w(0);
  if (tid < 256) { float sv = s_buf[b*256 + tid]; s_lds[tid] = sv; s2s[tid] = sv*sv; }
  // zero-fill: gw=0/65 columns (all hl), and OOR halo rows
  if (tid < 96) {
    int hl = tid >> 4, gw = ((tid >> 3) & 1) * 65, oc = tid & 7;
    int R = hl*66 + gw;
    *(u16x8*)((char*)x_lds + ((R*128 + oc*16) ^ ((R & 7) << 4))) = (u16x8)0;
  }
  if (h0 == 0) {
    int oc = tid & 7, gw = 1 + (tid >> 3);
    int R = gw;
    *(u16x8*)((char*)x_lds + ((R*128 + oc*16) ^ ((R & 7) << 4))) = (u16x8)0;
  }
  if (h0 == 60) {
    int oc = tid & 7, gw = 1 + (tid >> 3);
    int R = 5*66 + gw;
    *(u16x8*)((char*)x_lds + ((R*128 + oc*16) ^ ((R & 7) << 4))) = (u16x8)0;
  }
  __syncthreads();   // s_lds visible (also drains w(0) — once, cheap)

  {
    float4 v0[8], v1[8];
    if (do0) issue8(0, hl0, v0);
    if (do1) issue8(0, hl1, v1);
    // demod under the x-load latency: dms[co] = rsqrt(sum wsq[co,ci]*s^2 + eps)
    {
      int co = tid >> 1, half = tid & 1;
      const float4* row = (const float4*)(wsq + (size_t)co*256 + half*128);
      const float* sp = &s2s[half*128];
      float a = 0.f;
#pragma unroll 4
      for (int i = 0; i < 32; ++i) {
        float4 q = row[i];
        a += q.x*sp[4*i] + q.y*sp[4*i+1] + q.z*sp[4*i+2] + q.w*sp[4*i+3];
      }
      a += __shfl_xor(a, 1);
      if (half == 0) dms[co] = rsqrtf(a + EPS);
    }
    if (do0) write8(0, hl0, v0);
    if (do1) write8(0, hl1, v1);
  }
  __syncthreads();   // x(0), w(0), dms all visible

  f32x4 acc[4][8];
#pragma unroll
  for (int m = 0; m < 4; ++m)
#pragma unroll
    for (int f = 0; f < 8; ++f) acc[m][f] = (f32x4)0.f;

  // ---- main loop: 36 phases ----
  for (int c = 0; c < 4; ++c) {
    float4 v0[8], v1[8];
#pragma unroll
    for (int r = 0; r < 9; ++r) {
      int p = c*9 + r;
      if (r == 8 && c < 3) {             // issue next chunk's x loads (regs; no LDS hazard)
        if (do0) issue8(c + 1, hl0, v0);
        if (do1) issue8(c + 1, hl1, v1);
      }
      if (p < 35) stage_w(p + 1);        // async; drained by end-of-phase sync, under MFMA
      const unsigned short* wbp = &w_lds[(p & 1)*16384];
      int dh = r / 3, dw = r - dh*3;
#pragma unroll
      for (int kh = 0; kh < 2; ++kh) {
        int cio = kh*64 + lk*16;         // byte offset of this lane's 16B k-slice
        short8 a[4], bv[8];
#pragma unroll
        for (int m = 0; m < 4; ++m) {
          int co = wm*64 + m*16 + l15;
          int byte = (co*128 + cio) ^ ((co & 7) << 4);
          a[m] = *(const short8*)((const char*)wbp + byte);
        }
#pragma unroll
        for (int f = 0; f < 8; ++f) {
          int row = (wn*2 + (f >> 2) + dh)*66 + ((f & 3)*16 + l15 + dw);
          int byte = (row*128 + cio) ^ ((row & 7) << 4);
          bv[f] = *(const short8*)((const char*)x_lds + byte);
        }
        __builtin_amdgcn_s_setprio(1);
#pragma unroll
        for (int m = 0; m < 4; ++m)
#pragma unroll
          for (int f = 0; f < 8; ++f)
            acc[m][f] = __builtin_amdgcn_mfma_f32_16x16x32_bf16(a[m], bv[f], acc[m][f], 0, 0, 0);
        __builtin_amdgcn_s_setprio(0);
      }
      __syncthreads();                   // drain w(p+1) (+x reg loads at r==8); release LDS
      if (r == 8 && c < 3) {
        if (do0) write8(c + 1, hl0, v0);
        if (do1) write8(c + 1, hl1, v1);
        __syncthreads();                 // x(c+1) visible
      }
    }
  }

  // ---- epilogue: D col = lane&15 (w), row = (lane>>4)*4 + j (co offset) ----
  int colane = (lane >> 4) * 4;
#pragma unroll
  for (int m = 0; m < 4; ++m) {
    int cob = wm*64 + m*16 + colane;
    float4 d4 = *(const float4*)&dms[cob];
    float4 b4 = *(const float4*)&bias[cob];
#pragma unroll
    for (int f = 0; f < 8; ++f) {
      int h = h0 + wn*2 + (f >> 2);
      int wc = (f & 3)*16 + l15;
      float* op = out + ((size_t)(b*256 + cob)*64 + h)*64 + wc;
      op[0]     = acc[m][f][0] * d4.x + b4.x;
      op[4096]  = acc[m][f][1] * d4.y + b4.y;
      op[8192]  = acc[m][f][2] * d4.z + b4.z;
      op[12288] = acc[m][f][3] * d4.w + b4.w;
    }
  }
}

extern "C" void kernel_launch(void* const* d_in, const int* in_sizes, int n_in,
                              void* d_out, int out_size, void* d_ws, size_t ws_size,
                              hipStream_t stream) {
  const float* x      = (const float*)d_in[0];
  const float* style  = (const float*)d_in[1];
  const float* mw     = (const float*)d_in[2];
  const float* mb     = (const float*)d_in[3];
  const float* weight = (const float*)d_in[4];
  const float* bias   = (const float*)d_in[5];
  float* out = (float*)d_out;

  char* ws = (char*)d_ws;
  float* s_buf        = (float*)(ws);                             // 16 KB
  float* wsq          = (float*)(ws + 16384);                     // 256 KB
  unsigned short* wbf = (unsigned short*)(ws + 294912);           // 1.125 MB

  k_prep<<<272, 256, 0, stream>>>(style, mw, mb, s_buf, weight, wsq, wbf);
  k_conv<<<256, 512, 0, stream>>>(x, wbf, s_buf, wsq, bias, out);
}